// Round 9
// baseline (224.695 us; speedup 1.0000x reference)
//
#include <hip/hip_runtime.h>

// Correlation layer: out[b,o,h,w] = mean_c x1[b,c,h,w] * x2[b,c,h+dh,w+dw]
// B=8 C=128 H=W=128, d=4 -> 81 offsets (o = (dh+4)*9 + (dw+4)).
//
// R11: two independent barrier domains per CU. R7 (73us, best) is
// lockstep-bound: 1 WG/CU means all 9 waves queue 72 ds_reads at once
// after each barrier; the DS pipe serializes, the last wave's FMA tail
// extends the phase, everyone idles at the next barrier (VALUBusy 37%).
// R10 disproved the vmcnt-drain theory (raw barrier: no gain). R8 proved
// 2 WGs/CU lifts VALUBusy (49%) but its 4px/lane layout cost +30% VALU.
// R11 gets 2 WGs/CU while KEEPING the validated 8px/lane core: split the
// 9 dh per tile across two 320-thread WGs:
//   kind 0: waves 0..4 compute dh -4..0;  stages 4 x1 + 8 x2 rows
//   kind 1: waves 0..3 compute dh +1..+4; wave 4 = staging helper
// Per-wave work identical to R7 (72 FMA + 8 DPP per channel). 10 waves/CU
// -> 3-wave/SIMD register wall unchanged. DS ops/CU/step 88->96 (x1 staged
// twice); x2 global reads ~1.25x (L3-absorbed). The two WGs' barrier/DS
// phases interleave on the CU.
// Unchanged: split-halves LDS rows (16B lane stride, 0 conflicts), DPP
// row_shr1/shl1 halo (bound_ctrl=1 == zero-pad), post-barrier prefetch,
// XCD swizzle b=phys&7, plain __syncthreads.

constexpr int Cn = 128, Hn = 128, Wn = 128;
constexpr int HWn = Hn * Wn;
constexpr int TH = 4;
constexpr int NROWS = 12;           // 4 x1 rows + 8 x2 rows (kind1 uses 7+pad)
constexpr int ROWF  = 128;          // floats per LDS row
constexpr int CHF   = NROWS * ROWF; // 1536 floats per channel slab
constexpr int BUFF  = 2 * CHF;      // 3072 floats per buffer (2 channels)

__device__ __forceinline__ float dpp_shr1(float x) {  // lane l <- lane l-1 (0-fill)
  return __int_as_float(__builtin_amdgcn_update_dpp(
      0, __float_as_int(x), 0x111, 0xF, 0xF, true));
}
__device__ __forceinline__ float dpp_shl1(float x) {  // lane l <- lane l+1 (0-fill)
  return __int_as_float(__builtin_amdgcn_update_dpp(
      0, __float_as_int(x), 0x101, 0xF, 0xF, true));
}

__global__ __launch_bounds__(320, 3)
void corr_kernel(const float* __restrict__ x1, const float* __restrict__ x2,
                 float* __restrict__ out) {
  __shared__ float lds[2][2][NROWS][ROWF];  // [buf][ch][row][float] ; 24 KB

  const int t    = threadIdx.x;  // 0..319
  const int w    = t >> 6;       // wave 0..4
  const int lane = t & 63;
  const int r    = lane >> 4;    // output row 0..3
  const int l    = lane & 15;    // px group: px 8l..8l+7

  const int phys = blockIdx.x;   // 0..511
  const int b    = phys & 7;     // batch == XCD (round-robin assumption)
  const int slot = phys >> 3;    // 0..63
  const int kind = slot & 1;     // 0: dh -4..0 ; 1: dh +1..+4
  const int tile = slot >> 1;    // 0..31
  const int h0   = tile * TH;

  // ---- staging: primary slot for all 320 threads, secondary for t<64 ----
  // slab rows: 0..3 = x1 rows h0..h0+3 ; 4..11 = x2 rows h0+ridx-8+5*kind
  const int ridx = t >> 5;       // 0..9  (primary)
  const int s    = t & 31;
  const int j    = (s < 16) ? (s << 1) : (((s - 16) << 1) | 1); // global f4
  int grP; bool okP; const float* baseP;
  if (ridx < 4) { grP = h0 + ridx; okP = true; baseP = x1; }
  else { grP = h0 + ridx - 8 + 5 * kind; okP = ((unsigned)grP < (unsigned)Hn); baseP = x2; }
  const float* srcP = baseP + (size_t)b * Cn * HWn
                    + (size_t)(okP ? grP : 0) * Wn + (j << 2);
  const int woffP = ridx * ROWF + (s << 2);

  const bool sec = t < 64;       // secondary: rows 10,11
  const int ridx2 = 10 + (t >> 5);   // 10 or 11 (only meaningful for t<64)
  const int grS  = h0 + ridx2 - 8 + 5 * kind;
  const bool okS = sec && ((unsigned)grS < (unsigned)Hn);
  const float* srcS = x2 + (size_t)b * Cn * HWn
                    + (size_t)(okS ? grS : 0) * Wn + (j << 2);
  const int woffS = ridx2 * ROWF + (s << 2);

  float* const L = &lds[0][0][0][0];

  // ---- per-wave compute setup ----
  const bool active = (kind == 0) | (w < 4);  // kind1 wave4: staging only
  const int dhi = w + 5 * kind;               // output dh index 0..8
  const int rxi = r + w + 4;                  // staged x2 row 4..11 (both kinds)
  const int o1l = r * ROWF + (l << 2);
  const int o1h = o1l + 64;
  const int o2l = rxi * ROWF + (l << 2);
  const int o2h = o2l + 64;

  float4 acc0[9], acc1[9];
#pragma unroll
  for (int dw = 0; dw < 9; ++dw) {
    acc0[dw] = make_float4(0.f, 0.f, 0.f, 0.f);
    acc1[dw] = make_float4(0.f, 0.f, 0.f, 0.f);
  }

  // prologue: prefetch channels 0,1
  const float4 z4 = make_float4(0.f, 0.f, 0.f, 0.f);
  float4 pv0 = z4, pv1 = z4, pw0 = z4, pw1 = z4;
  if (okP) { pv0 = *(const float4*)srcP; pv1 = *(const float4*)(srcP + HWn); }
  if (okS) { pw0 = *(const float4*)srcS; pw1 = *(const float4*)(srcS + HWn); }
  srcP += 2 * (size_t)HWn;
  srcS += 2 * (size_t)HWn;

#pragma unroll 1
  for (int step = 0; step < 64; ++step) {
    const int bo = (step & 1) * BUFF;
    *(float4*)(L + bo + woffP)       = pv0;   // channel 2*step
    *(float4*)(L + bo + CHF + woffP) = pv1;   // channel 2*step+1
    if (sec) {
      *(float4*)(L + bo + woffS)       = pw0;
      *(float4*)(L + bo + CHF + woffS) = pw1;
    }
    __syncthreads();
    // prefetch next slab AFTER the barrier; consumed at next ds_write
    if (step < 63) {
      if (okP) { pv0 = *(const float4*)srcP; pv1 = *(const float4*)(srcP + HWn); }
      if (okS) { pw0 = *(const float4*)srcS; pw1 = *(const float4*)(srcS + HWn); }
    }
    srcP += 2 * (size_t)HWn;
    srcS += 2 * (size_t)HWn;

    if (active) {
#pragma unroll
      for (int ch = 0; ch < 2; ++ch) {
        const float* p = L + bo + ch * CHF;
        const float4 a0 = *(const float4*)(p + o1l);
        const float4 a1 = *(const float4*)(p + o1h);
        const float4 b0 = *(const float4*)(p + o2l);
        const float4 b1 = *(const float4*)(p + o2h);
        // win[k] = x2[px 8l + k - 4], k = 0..15
        const float win[16] = {
            dpp_shr1(b1.x), dpp_shr1(b1.y), dpp_shr1(b1.z), dpp_shr1(b1.w),
            b0.x, b0.y, b0.z, b0.w,
            b1.x, b1.y, b1.z, b1.w,
            dpp_shl1(b0.x), dpp_shl1(b0.y), dpp_shl1(b0.z), dpp_shl1(b0.w)};
        const float av[8] = {a0.x, a0.y, a0.z, a0.w, a1.x, a1.y, a1.z, a1.w};
#pragma unroll
        for (int dw = 0; dw < 9; ++dw) {
          acc0[dw].x += av[0] * win[dw + 0];
          acc0[dw].y += av[1] * win[dw + 1];
          acc0[dw].z += av[2] * win[dw + 2];
          acc0[dw].w += av[3] * win[dw + 3];
          acc1[dw].x += av[4] * win[dw + 4];
          acc1[dw].y += av[5] * win[dw + 5];
          acc1[dw].z += av[6] * win[dw + 6];
          acc1[dw].w += av[7] * win[dw + 7];
        }
      }
    }
  }

  // ---- epilogue: scale + store (each active wave owns its dh) ----
  if (active) {
    const float scale = 1.0f / 128.0f;
    float* ob = out + ((size_t)b * 81 + (size_t)dhi * 9) * HWn
                    + (size_t)(h0 + r) * Wn + (l << 3);
#pragma unroll
    for (int dw = 0; dw < 9; ++dw) {
      float4 r0, r1;
      r0.x = acc0[dw].x * scale; r0.y = acc0[dw].y * scale;
      r0.z = acc0[dw].z * scale; r0.w = acc0[dw].w * scale;
      r1.x = acc1[dw].x * scale; r1.y = acc1[dw].y * scale;
      r1.z = acc1[dw].z * scale; r1.w = acc1[dw].w * scale;
      *(float4*)(ob + (size_t)dw * HWn)     = r0;
      *(float4*)(ob + (size_t)dw * HWn + 4) = r1;
    }
  }
}

extern "C" void kernel_launch(void* const* d_in, const int* in_sizes, int n_in,
                              void* d_out, int out_size, void* d_ws, size_t ws_size,
                              hipStream_t stream) {
  const float* x1 = (const float*)d_in[0];
  const float* x2 = (const float*)d_in[1];
  float* out = (float*)d_out;
  const int n_wgs = 8 * (Hn / TH) * 2;  // 512 WGs = 2 per CU
  corr_kernel<<<dim3(n_wgs), dim3(320), 0, stream>>>(x1, x2, out);
}

// Round 11
// 184.185 us; speedup vs baseline: 1.2199x; 1.2199x over previous
//
#include <hip/hip_runtime.h>

// Correlation layer: out[b,o,h,w] = mean_c x1[b,c,h,w] * x2[b,c,h+dh,w+dw]
// B=8 C=128 H=W=128, d=4 -> 81 offsets (o = (dh+4)*9 + (dw+4)).
//
// R13 = R12 resubmitted verbatim (R12's bench died to an infra error:
// "MI355X container failed twice"; kernel re-audited, no fault found).
//
// R12: three symmetric barrier domains per CU. Evidence: R7 (9-wave WG,
// 1 domain/CU) = 73us @ VALUBusy 37% (lockstep: all waves stall in the
// same ds_write->barrier->ds_read->FMA chain); R8 proved 2 domains lift
// VALUBusy to 49% but its 4px/lane layout added ~30% VALU work; R10
// proved the vmcnt-drain-at-barrier is NOT the stall; R11's asymmetric
// 320-thr split broke dispatch (Occupancy 13%). R12: WG = 192 thr =
// 3 waves = 3 consecutive dh (wave w <-> dh dhm+w), grid = 8b x 32tiles
// x 3groups = 768 WGs = 3 WGs/CU (the grid shape that measurably
// co-resided 3/CU in R1-R3). Per-wave compute core is R7's, unchanged:
// 8px/lane, 16-lane DPP row_shr1/shl1 halo (bound_ctrl=1 zero-fill ==
// zero-pad), split-halves LDS rows (16B lane stride, 0 conflicts
// measured), acc[9 dw] x 2 f4, 72 FMA + 8 DPP per channel.
//  - staging: 10 rows/slab (4 x1 + 6 x2), slab 1280 f; 2ch x 2buf = 20KB.
//    Thread t writes f4 slot t (offset 4t) and t+192 (t<128, offset
//    4t+768): row = slot>>5, col c = slot&31, global f4
//    j = (c<16) ? 2c : 2(c-16)+1 (split-halves). Writes 16B-stride.
//  - OOB x2 rows stage zeros. x1 staged per-WG (3x/CU, L1/L2-absorbed).
//  - post-barrier prefetch (consumed at next ds_write), plain
//    __syncthreads, 2 channels per barrier.

constexpr int Cn = 128, Hn = 128, Wn = 128;
constexpr int HWn = Hn * Wn;
constexpr int TH = 4;
constexpr int NROWS = 10;           // 4 x1 rows + 6 x2 rows
constexpr int ROWF  = 128;          // floats per LDS row
constexpr int CHF   = NROWS * ROWF; // 1280 floats per channel slab
constexpr int BUFF  = 2 * CHF;      // 2560 floats per buffer (2 channels)

__device__ __forceinline__ float dpp_shr1(float x) {  // lane l <- lane l-1 (0-fill)
  return __int_as_float(__builtin_amdgcn_update_dpp(
      0, __float_as_int(x), 0x111, 0xF, 0xF, true));
}
__device__ __forceinline__ float dpp_shl1(float x) {  // lane l <- lane l+1 (0-fill)
  return __int_as_float(__builtin_amdgcn_update_dpp(
      0, __float_as_int(x), 0x101, 0xF, 0xF, true));
}

__global__ __launch_bounds__(192, 3)
void corr_kernel(const float* __restrict__ x1, const float* __restrict__ x2,
                 float* __restrict__ out) {
  __shared__ float lds[2][2][NROWS][ROWF];  // [buf][ch][row][float] ; 20 KB

  const int t    = threadIdx.x;  // 0..191
  const int w    = t >> 6;       // wave 0..2 -> dh = dhm + w
  const int lane = t & 63;
  const int r    = lane >> 4;    // output row 0..3
  const int l    = lane & 15;    // px group: px 8l..8l+7

  const int phys = blockIdx.x;   // 0..767
  const int b    = phys & 7;     // batch == XCD (round-robin assumption)
  const int slot = phys >> 3;    // 0..95
  const int tile = slot / 3;     // 0..31
  const int g    = slot - tile * 3;  // dh group 0..2
  const int h0   = tile * TH;
  const int dhm  = g * 3 - 4;    // first dh of group: -4, -1, +2

  // ---- staging slots: sA = t (rows 0..5), sB = t+192 (rows 6..9, t<128) ----
  // slab rows: 0..3 = x1 rows h0+row ; 4..9 = x2 rows h0+dhm+(row-4)
  const int cA = t & 31, rowA = t >> 5;
  const int jA = (cA < 16) ? (cA << 1) : (((cA - 16) << 1) | 1);
  int grA; bool okA; const float* baseA;
  if (rowA < 4) { grA = h0 + rowA; okA = true; baseA = x1; }
  else { grA = h0 + dhm + rowA - 4; okA = ((unsigned)grA < (unsigned)Hn); baseA = x2; }
  const float* srcA = baseA + (size_t)b * Cn * HWn
                    + (size_t)(okA ? grA : 0) * Wn + (jA << 2);
  const int woffA = t << 2;          // rowA*128 + 4*cA

  const bool actB = t < 128;
  const int sB = t + 192;
  const int cB = sB & 31, rowB = sB >> 5;   // rows 6..9 (x2)
  const int jB = (cB < 16) ? (cB << 1) : (((cB - 16) << 1) | 1);
  const int grB = h0 + dhm + rowB - 4;
  const bool okB = actB && ((unsigned)grB < (unsigned)Hn);
  const float* srcB = x2 + (size_t)b * Cn * HWn
                    + (size_t)(okB ? grB : 0) * Wn + (jB << 2);
  const int woffB = sB << 2;

  float* const L = &lds[0][0][0][0];

  // ---- per-wave read offsets (within slab) ----
  const int o1l = r * ROWF + (l << 2);          // x1 row r, low f4
  const int o1h = o1l + 64;
  const int o2l = (4 + r + w) * ROWF + (l << 2); // x2 staged row 4+r+w
  const int o2h = o2l + 64;

  float4 acc0[9], acc1[9];
#pragma unroll
  for (int dw = 0; dw < 9; ++dw) {
    acc0[dw] = make_float4(0.f, 0.f, 0.f, 0.f);
    acc1[dw] = make_float4(0.f, 0.f, 0.f, 0.f);
  }

  // prologue: prefetch channels 0,1 for both slots
  const float4 z4 = make_float4(0.f, 0.f, 0.f, 0.f);
  float4 pvA0 = z4, pvA1 = z4, pvB0 = z4, pvB1 = z4;
  if (okA) { pvA0 = *(const float4*)srcA; pvA1 = *(const float4*)(srcA + HWn); }
  if (okB) { pvB0 = *(const float4*)srcB; pvB1 = *(const float4*)(srcB + HWn); }
  srcA += 2 * (size_t)HWn;
  srcB += 2 * (size_t)HWn;

#pragma unroll 1
  for (int step = 0; step < 64; ++step) {
    const int bo = (step & 1) * BUFF;
    *(float4*)(L + bo + woffA)       = pvA0;   // channel 2*step
    *(float4*)(L + bo + CHF + woffA) = pvA1;   // channel 2*step+1
    if (actB) {
      *(float4*)(L + bo + woffB)       = pvB0;
      *(float4*)(L + bo + CHF + woffB) = pvB1;
    }
    __syncthreads();
    // prefetch next slab AFTER the barrier (hipcc drains vmcnt(0) before
    // s_barrier); consumed at next step's ds_write
    if (step < 63) {
      if (okA) { pvA0 = *(const float4*)srcA; pvA1 = *(const float4*)(srcA + HWn); }
      if (okB) { pvB0 = *(const float4*)srcB; pvB1 = *(const float4*)(srcB + HWn); }
    }
    srcA += 2 * (size_t)HWn;
    srcB += 2 * (size_t)HWn;

#pragma unroll
    for (int ch = 0; ch < 2; ++ch) {
      const float* p = L + bo + ch * CHF;
      const float4 a0 = *(const float4*)(p + o1l);
      const float4 a1 = *(const float4*)(p + o1h);
      const float4 b0 = *(const float4*)(p + o2l);
      const float4 b1 = *(const float4*)(p + o2h);
      // win[k] = x2[px 8l + k - 4], k = 0..15
      const float win[16] = {
          dpp_shr1(b1.x), dpp_shr1(b1.y), dpp_shr1(b1.z), dpp_shr1(b1.w),
          b0.x, b0.y, b0.z, b0.w,
          b1.x, b1.y, b1.z, b1.w,
          dpp_shl1(b0.x), dpp_shl1(b0.y), dpp_shl1(b0.z), dpp_shl1(b0.w)};
      const float av[8] = {a0.x, a0.y, a0.z, a0.w, a1.x, a1.y, a1.z, a1.w};
#pragma unroll
      for (int dw = 0; dw < 9; ++dw) {
        acc0[dw].x += av[0] * win[dw + 0];
        acc0[dw].y += av[1] * win[dw + 1];
        acc0[dw].z += av[2] * win[dw + 2];
        acc0[dw].w += av[3] * win[dw + 3];
        acc1[dw].x += av[4] * win[dw + 4];
        acc1[dw].y += av[5] * win[dw + 5];
        acc1[dw].z += av[6] * win[dw + 6];
        acc1[dw].w += av[7] * win[dw + 7];
      }
    }
  }

  // ---- epilogue: scale + store (each wave owns its dh entirely) ----
  const float scale = 1.0f / 128.0f;
  const int dhi = g * 3 + w;
  float* ob = out + ((size_t)b * 81 + (size_t)dhi * 9) * HWn
                  + (size_t)(h0 + r) * Wn + (l << 3);
#pragma unroll
  for (int dw = 0; dw < 9; ++dw) {
    float4 r0, r1;
    r0.x = acc0[dw].x * scale; r0.y = acc0[dw].y * scale;
    r0.z = acc0[dw].z * scale; r0.w = acc0[dw].w * scale;
    r1.x = acc1[dw].x * scale; r1.y = acc1[dw].y * scale;
    r1.z = acc1[dw].z * scale; r1.w = acc1[dw].w * scale;
    *(float4*)(ob + (size_t)dw * HWn)     = r0;
    *(float4*)(ob + (size_t)dw * HWn + 4) = r1;
  }
}

extern "C" void kernel_launch(void* const* d_in, const int* in_sizes, int n_in,
                              void* d_out, int out_size, void* d_ws, size_t ws_size,
                              hipStream_t stream) {
  const float* x1 = (const float*)d_in[0];
  const float* x2 = (const float*)d_in[1];
  float* out = (float*)d_out;
  const int n_wgs = 8 * (Hn / TH) * 3;  // 768 WGs = 3 per CU
  corr_kernel<<<dim3(n_wgs), dim3(192), 0, stream>>>(x1, x2, out);
}